// Round 2
// baseline (20892.888 us; speedup 1.0000x reference)
//
#include <hip/hip_runtime.h>
#include <stdint.h>

#define BB 512
#define TT 256
#define FF 128
#define HH 256
#define G4 1024   // 4*H
#define K2 512    // gates K: 128 c_c + 128 m + 256 h
#define NBLK 256
#define EPSL 1e-9f

// ws element offsets (uint16 units). All weights packed as [k/4][out][4]
// so one uint2 load = 4 consecutive-k bf16 weights for one output column.
#define E_WDH 0         // k<128, out 256  -> 32768 elems
#define E_WH  32768     // k<256, out 128  -> 32768
#define E_WF  65536     // k<128, out 128  -> 16384 (diag pre-zeroed)
#define E_WC  81920     // k<256, out 128  -> 32768
#define E_W2  114688    // k<512, out 1024 -> 524288 (Wih|Whh stacked over k)
#define E_END 638976
#define OFF_MSUM (E_END * 2)           // f32 [256]
#define OFF_PART (OFF_MSUM + 1024)     // f32 [3][256][256]

__device__ __forceinline__ uint16_t f2bf(float v) {
    uint32_t u = __float_as_uint(v);
    uint32_t r = (u + 0x7fffu + ((u >> 16) & 1u)) >> 16;  // RNE
    return (uint16_t)r;
}
__device__ __forceinline__ float fexp(float x) { return __expf(x); }
__device__ __forceinline__ float fsigm(float x) { return 1.f / (1.f + __expf(-x)); }
__device__ __forceinline__ float ftanh(float x) {
    float e = __expf(2.f * x);
    return 1.f - 2.f / (e + 1.f);   // safe at +/-inf
}

// ---------------- prep: convert weights to packed-transposed bf16 in ws ----------------
__global__ void prep_weights(const float* __restrict__ Wdh, const float* __restrict__ Wh,
                             const float* __restrict__ Wf, const float* __restrict__ Wc,
                             const float* __restrict__ Wih, const float* __restrict__ Whh,
                             uint16_t* __restrict__ wsu) {
    const int total = 638976;
    for (int i = blockIdx.x * blockDim.x + threadIdx.x; i < total; i += gridDim.x * blockDim.x) {
        float v; int dst;
        if (i < 32768) {            // Wdh [256 out, 128 k]
            int o = i, k = o >> 8, j = o & 255;
            v = Wdh[j * 128 + k];
            dst = E_WDH + ((k >> 2) * 256 + j) * 4 + (k & 3);
        } else if (i < 65536) {     // Wh [128 out, 256 k]
            int o = i - 32768, k = o >> 7, f = o & 127;
            v = Wh[f * 256 + k];
            dst = E_WH + ((k >> 2) * 128 + f) * 4 + (k & 3);
        } else if (i < 81920) {     // Wf [128,128], diag masked
            int o = i - 65536, k = o >> 7, f = o & 127;
            v = (k == f) ? 0.f : Wf[f * 128 + k];
            dst = E_WF + ((k >> 2) * 128 + f) * 4 + (k & 3);
        } else if (i < 114688) {    // Wc [128 out, 256 k]
            int o = i - 81920, k = o >> 7, f = o & 127;
            v = Wc[f * 256 + k];
            dst = E_WC + ((k >> 2) * 128 + f) * 4 + (k & 3);
        } else {                    // W2 [1024 out, 512 k]: k<256 Wih, else Whh
            int o = i - 114688, k = o >> 10, g = o & 1023;
            v = (k < 256) ? Wih[g * 256 + k] : Whh[g * 256 + (k - 256)];
            dst = E_W2 + ((k >> 2) * 1024 + g) * 4 + (k & 3);
        }
        wsu[dst] = f2bf(v);
    }
}

// ---------------- msum[t] = sum over B,F of mask[:,t,:] ----------------
__global__ void msum_kernel(const float* __restrict__ mask, float* __restrict__ msum) {
    int t = blockIdx.x;
    float s = 0.f;
    for (int i = threadIdx.x; i < BB * FF; i += 256) {
        int b = i >> 7, f = i & 127;
        s += mask[((long)b * TT + t) * FF + f];
    }
    __shared__ float red[4];
    for (int off = 32; off; off >>= 1) s += __shfl_down(s, off);
    if ((threadIdx.x & 63) == 0) red[threadIdx.x >> 6] = s;
    __syncthreads();
    if (threadIdx.x == 0) msum[t] = red[0] + red[1] + red[2] + red[3];
}

#define UNPACK4(w, w0, w1, w2, w3)                     \
    float w0 = __uint_as_float((w).x << 16);           \
    float w1 = __uint_as_float((w).x & 0xffff0000u);   \
    float w2 = __uint_as_float((w).y << 16);           \
    float w3 = __uint_as_float((w).y & 0xffff0000u);

// ---------------- main scan: 256 blocks x 1024 threads, 2 rows/block, K-split ----------------
__launch_bounds__(1024, 4)
__global__ void rits_main(const float* __restrict__ values, const float* __restrict__ mask,
                          const float* __restrict__ deltas,
                          const float* __restrict__ bdh, const float* __restrict__ Wdx,
                          const float* __restrict__ bdx, const float* __restrict__ bh,
                          const float* __restrict__ bf_, const float* __restrict__ bc_,
                          const float* __restrict__ bih, const float* __restrict__ bhh,
                          const uint16_t* __restrict__ wsu,
                          float* __restrict__ part, float* __restrict__ out_imp) {
    __shared__ __align__(16) float h_lds[2 * HH];
    __shared__ __align__(16) float m_lds[2 * FF];
    __shared__ __align__(16) float d_lds[2 * FF];
    __shared__ __align__(16) float gx_lds[2 * FF];
    __shared__ __align__(16) float xc_lds[2 * FF];
    __shared__ __align__(16) float act_lds[2 * K2];   // per row: [cc 128 | m 128 | h 256]
    __shared__ __align__(16) float redA[1024];
    __shared__ __align__(16) float redB[1024];
    __shared__ __align__(16) float gate_lds[2 * G4];
    __shared__ float wred[3][4];

    const int tid = threadIdx.x;
    const int blk = blockIdx.x;
    const int r0 = blk * 2;

    const uint2* WdhP = (const uint2*)(wsu + E_WDH);
    const uint2* WhP  = (const uint2*)(wsu + E_WH);
    const uint2* WfP  = (const uint2*)(wsu + E_WF);
    const uint2* WcP  = (const uint2*)(wsu + E_WC);
    const uint2* W2P  = (const uint2*)(wsu + E_W2);

    // thread-role indices
    const int f_a = tid & 127;          // phases A/D/E/F/G
    const int rr_a = (tid >> 7) & 1;    // row for A/E/G (tid<256)
    const int j2_b = tid & 255;         // phases B/C/I
    const int rr_b = (tid >> 8) & 1;
    const int kh_b = tid >> 9;          // B: K-half
    const int rr_d = (tid >> 7) & 1;    // D/F row
    const int kq_d = tid >> 8;          // D/F: K-quarter

    // hoisted constants
    float c_wdx = 0.f, c_bdx = 0.f, c_bh = 0.f, c_bf = 0.f, c_bc = 0.f;
    if (tid < 256) {
        c_wdx = Wdx[f_a * FF + f_a];
        c_bdx = bdx[f_a];
        c_bh = bh[f_a]; c_bf = bf_[f_a]; c_bc = bc_[f_a];
    }
    const float c_bdh = (tid < 512) ? bdh[j2_b] : 0.f;
    const float c_bg = bih[tid] + bhh[tid];

    float cst = 0.f;                     // c-state owner: tid<512 -> (rr_b, j2_b)
    if (tid < 512) h_lds[tid] = 0.f;
    __syncthreads();

    for (int t = 0; t < TT; ++t) {
        float xv = 0.f, mv = 0.f, acc1 = 0.f, xh = 0.f;
        // ---- A: stage m, d, gamma_x (tid<256) ----
        if (tid < 256) {
            long src = ((long)(r0 + rr_a) * TT + t) * FF + f_a;
            xv = values[src]; mv = mask[src];
            float dv = deltas[src];
            m_lds[tid] = mv; d_lds[tid] = dv;
            gx_lds[tid] = fexp(-fmaxf(dv * c_wdx + c_bdx, 0.f));
        }
        __syncthreads();  // S1

        // ---- B: gamma_h partials (512 outputs x 2 K-halves of 64) ----
        {
            float s = (tid < 512) ? c_bdh : 0.f;
            const float4* dv4 = (const float4*)(d_lds + rr_b * FF);
            const int kb0 = kh_b * 16;
            #pragma unroll
            for (int i = 0; i < 16; ++i) {
                int kb = kb0 + i;
                uint2 w = WdhP[kb * 256 + j2_b];
                float4 dd = dv4[kb];
                UNPACK4(w, w0, w1, w2, w3)
                s = fmaf(dd.x, w0, s); s = fmaf(dd.y, w1, s);
                s = fmaf(dd.z, w2, s); s = fmaf(dd.w, w3, s);
            }
            redA[tid] = s;
        }
        __syncthreads();  // S2

        // ---- C: combine gamma_h, decay h (tid<512) ----
        if (tid < 512) {
            float g = redA[tid] + redA[tid + 512];
            float hv = h_lds[tid] * fexp(-fmaxf(g, 0.f));
            h_lds[tid] = hv;
            act_lds[rr_b * K2 + 256 + j2_b] = hv;
        }
        __syncthreads();  // S3

        // ---- D: x_h partials (256 outputs x 4 K-quarters of 64) ----
        {
            float s = 0.f;
            const float4* hv4 = (const float4*)(h_lds + rr_d * HH);
            const int kb0 = kq_d * 16;
            #pragma unroll
            for (int i = 0; i < 16; ++i) {
                int kb = kb0 + i;
                uint2 w = WhP[kb * 128 + f_a];
                float4 hh = hv4[kb];
                UNPACK4(w, w0, w1, w2, w3)
                s = fmaf(hh.x, w0, s); s = fmaf(hh.y, w1, s);
                s = fmaf(hh.z, w2, s); s = fmaf(hh.w, w3, s);
            }
            redA[tid] = s;
        }
        __syncthreads();  // S4

        // ---- E: combine x_h, loss1, x_c (tid<256) ----
        if (tid < 256) {
            xh = c_bh + redA[tid] + redA[tid + 256] + redA[tid + 512] + redA[tid + 768];
            acc1 = fabsf(xh - xv) * mv;
            xc_lds[tid] = mv * xv + (1.f - mv) * xh;
        }
        __syncthreads();  // S5

        // ---- F: z_h partials + alpha partials ----
        {
            float s1 = 0.f;
            const float4* xc4 = (const float4*)(xc_lds + rr_d * FF);
            const int kbz0 = kq_d * 8;
            #pragma unroll
            for (int i = 0; i < 8; ++i) {
                int kb = kbz0 + i;
                uint2 w = WfP[kb * 128 + f_a];
                float4 xc = xc4[kb];
                UNPACK4(w, w0, w1, w2, w3)
                s1 = fmaf(xc.x, w0, s1); s1 = fmaf(xc.y, w1, s1);
                s1 = fmaf(xc.z, w2, s1); s1 = fmaf(xc.w, w3, s1);
            }
            redA[tid] = s1;

            float s2 = 0.f;
            const float4* src4 = (kq_d < 2) ? (const float4*)(gx_lds + rr_d * FF)
                                            : (const float4*)(m_lds + rr_d * FF);
            const int kbw0 = kq_d * 16;          // weight kb over full K=256
            const int kbs0 = (kq_d & 1) * 16;    // source kb within its 128 half
            #pragma unroll
            for (int i = 0; i < 16; ++i) {
                uint2 w = WcP[(kbw0 + i) * 128 + f_a];
                float4 sv = src4[kbs0 + i];
                UNPACK4(w, w0, w1, w2, w3)
                s2 = fmaf(sv.x, w0, s2); s2 = fmaf(sv.y, w1, s2);
                s2 = fmaf(sv.z, w2, s2); s2 = fmaf(sv.w, w3, s2);
            }
            redB[tid] = s2;
        }
        __syncthreads();  // S6

        // ---- G: combine z_h/alpha, losses, c_c, stage act (tid<256) ----
        if (tid < 256) {
            float zh = c_bf + redA[tid] + redA[tid + 256] + redA[tid + 512] + redA[tid + 768];
            float alpha = c_bc + redB[tid] + redB[tid + 256] + redB[tid + 512] + redB[tid + 768];
            float acc2 = fabsf(zh - xv) * mv;
            float ch = alpha * zh + (1.f - alpha) * xh;
            float acc3 = fabsf(ch - xv) * mv;
            float cc = mv * xv + (1.f - mv) * ch;
            out_imp[((long)(r0 + rr_a) * TT + t) * FF + f_a] = cc;
            act_lds[rr_a * K2 + f_a] = cc;
            act_lds[rr_a * K2 + FF + f_a] = mv;
            float a1 = acc1, a2 = acc2, a3 = acc3;
            for (int off = 32; off; off >>= 1) {
                a1 += __shfl_down(a1, off);
                a2 += __shfl_down(a2, off);
                a3 += __shfl_down(a3, off);
            }
            if ((tid & 63) == 0) {
                wred[0][tid >> 6] = a1; wred[1][tid >> 6] = a2; wred[2][tid >> 6] = a3;
            }
        }
        __syncthreads();  // S7

        // ---- H: gates GEMV, thread = gate-output g4 = tid, both rows ----
        if (tid < 3)
            part[((long)tid * TT + t) * NBLK + blk] =
                wred[tid][0] + wred[tid][1] + wred[tid][2] + wred[tid][3];
        {
            float g0 = c_bg, g1 = c_bg;
            const float4* a0v = (const float4*)act_lds;
            const float4* a1v = (const float4*)(act_lds + K2);
            #pragma unroll 4
            for (int kb = 0; kb < 128; ++kb) {
                uint2 w = W2P[kb * G4 + tid];
                float4 a0 = a0v[kb];
                float4 a1 = a1v[kb];
                UNPACK4(w, w0, w1, w2, w3)
                g0 = fmaf(a0.x, w0, g0); g1 = fmaf(a1.x, w0, g1);
                g0 = fmaf(a0.y, w1, g0); g1 = fmaf(a1.y, w1, g1);
                g0 = fmaf(a0.z, w2, g0); g1 = fmaf(a1.z, w2, g1);
                g0 = fmaf(a0.w, w3, g0); g1 = fmaf(a1.w, w3, g1);
            }
            gate_lds[tid] = g0;
            gate_lds[G4 + tid] = g1;
        }
        __syncthreads();  // S8

        // ---- I: LSTM pointwise update (tid<512) ----
        if (tid < 512) {
            const float* gl = gate_lds + rr_b * G4;
            float gi = gl[j2_b], gf = gl[256 + j2_b], gg = gl[512 + j2_b], go = gl[768 + j2_b];
            cst = fsigm(gf) * cst + fsigm(gi) * ftanh(gg);
            float hn = fsigm(go) * ftanh(cst);
            h_lds[tid] = hn;
        }
        // next-iteration S1/S2 order h_lds reuse; A's buffers have no pending readers
    }
}

// ---------------- finisher: assemble the two scalar losses ----------------
__global__ void finisher(const float* __restrict__ part, const float* __restrict__ msum,
                         float* __restrict__ out2) {
    int t = threadIdx.x;  // 256 threads == 256 timesteps
    float s1 = 0.f, s2 = 0.f, s3 = 0.f;
    const float* p1 = part + ((long)0 * TT + t) * NBLK;
    const float* p2 = part + ((long)1 * TT + t) * NBLK;
    const float* p3 = part + ((long)2 * TT + t) * NBLK;
    for (int b = 0; b < NBLK; ++b) { s1 += p1[b]; s2 += p2[b]; s3 += p3[b]; }
    float den = msum[t] + EPSL;
    float l12 = (s1 + s2) / den;
    float l3  = s3 / den;
    float xl = l12 + (float)(TT - t) * l3;  // l3_t counted (T-t) times in x_loss
    float ml = l3;
    __shared__ float r1[4], r2[4];
    for (int off = 32; off; off >>= 1) {
        xl += __shfl_down(xl, off);
        ml += __shfl_down(ml, off);
    }
    if ((t & 63) == 0) { r1[t >> 6] = xl; r2[t >> 6] = ml; }
    __syncthreads();
    if (t == 0) {
        float X = r1[0] + r1[1] + r1[2] + r1[3];
        float M = r2[0] + r2[1] + r2[2] + r2[3];
        out2[0] = X / (float)(TT * 3);
        out2[1] = M / (float)TT;
    }
}

extern "C" void kernel_launch(void* const* d_in, const int* in_sizes, int n_in,
                              void* d_out, int out_size, void* d_ws, size_t ws_size,
                              hipStream_t stream) {
    const float* values = (const float*)d_in[0];
    const float* mask   = (const float*)d_in[1];
    const float* deltas = (const float*)d_in[2];
    const float* Wdh = (const float*)d_in[3];
    const float* bdh = (const float*)d_in[4];
    const float* Wdx = (const float*)d_in[5];
    const float* bdx = (const float*)d_in[6];
    const float* Wh  = (const float*)d_in[7];
    const float* bh  = (const float*)d_in[8];
    const float* Wf  = (const float*)d_in[9];
    const float* bf_ = (const float*)d_in[10];
    const float* Wc  = (const float*)d_in[11];
    const float* bc_ = (const float*)d_in[12];
    const float* Wih = (const float*)d_in[13];
    const float* Whh = (const float*)d_in[14];
    const float* bih = (const float*)d_in[15];
    const float* bhh = (const float*)d_in[16];

    float* out = (float*)d_out;
    uint16_t* wsu = (uint16_t*)d_ws;
    float* msum = (float*)((char*)d_ws + OFF_MSUM);
    float* part = (float*)((char*)d_ws + OFF_PART);

    prep_weights<<<2496, 256, 0, stream>>>(Wdh, Wh, Wf, Wc, Wih, Whh, wsu);
    msum_kernel<<<TT, 256, 0, stream>>>(mask, msum);
    rits_main<<<NBLK, 1024, 0, stream>>>(values, mask, deltas, bdh, Wdx, bdx,
                                         bh, bf_, bc_, bih, bhh, wsu, part, out);
    finisher<<<1, 256, 0, stream>>>(part, msum, out + (long)BB * TT * FF);
}

// Round 3
// 9248.141 us; speedup vs baseline: 2.2591x; 2.2591x over previous
//
#include <hip/hip_runtime.h>
#include <stdint.h>

#define BB 512
#define TT 256
#define FF 128
#define HH 256
#define NB 32          // blocks (16 rows each)
#define MR 16
#define EPSL 1e-9f

// ws bf16-element offsets. B-fragment-swizzled: [kt][nt][lane][8],
// elem (kt,nt,lane,j) holds B[k=kt*32+(lane>>4)*8+j][n=nt*16+(lane&15)]
#define E_WDH 0        // kt 4, nt 16  (gamma_h: K=128, N=256)
#define E_WH  32768    // kt 8, nt 8   (x_h:    K=256, N=128)
#define E_WF  65536    // kt 4, nt 8   (z_h:    K=128, N=128, diag zeroed)
#define E_WC  81920    // kt 8, nt 8   (alpha:  K=256, N=128)
#define E_W2  114688   // kt 16, nt 64 (gates:  K=512, N=1024)
#define E_END 638976
#define OFF_MSUM (E_END * 2)            // f32 [256]
#define OFF_PART (OFF_MSUM + 1024)      // f32 [3][TT][NB]

typedef __attribute__((ext_vector_type(8))) short s8v;   // 8 bf16
typedef __attribute__((ext_vector_type(4))) float f4v;   // 4 f32

__device__ __forceinline__ uint16_t f2bf(float v) {
    uint32_t u = __float_as_uint(v);
    return (uint16_t)((u + 0x7fffu + ((u >> 16) & 1u)) >> 16);  // RNE
}
__device__ __forceinline__ float fexp(float x) { return __expf(x); }
__device__ __forceinline__ float fsigm(float x) { return 1.f / (1.f + __expf(-x)); }
__device__ __forceinline__ float ftanh(float x) {
    float e = __expf(2.f * x);
    return 1.f - 2.f / (e + 1.f);
}
__device__ __forceinline__ uint2 pack4(float a, float b, float c, float d) {
    uint2 r;
    r.x = (uint32_t)f2bf(a) | ((uint32_t)f2bf(b) << 16);
    r.y = (uint32_t)f2bf(c) | ((uint32_t)f2bf(d) << 16);
    return r;
}
// A-swizzled LDS index for element (k, m): lane=(k>>3 &3)*16+m, chunk j=k&7
__device__ __forceinline__ int aidx(int k, int m) {
    return ((k >> 5) << 9) + (((((k >> 3) & 3) << 4) + m) << 3) + (k & 7);
}

// ---------------- prep: pack weights into B-fragment bf16 layout ----------------
__global__ void prep_weights(const float* __restrict__ Wdh, const float* __restrict__ Wh,
                             const float* __restrict__ Wf, const float* __restrict__ Wc,
                             const float* __restrict__ Wih, const float* __restrict__ Whh,
                             uint16_t* __restrict__ wsu) {
    const int total = E_END;
    for (int i = blockIdx.x * blockDim.x + threadIdx.x; i < total; i += gridDim.x * blockDim.x) {
        float v;
        if (i < 32768) {                        // WdhB
            int o = i, j = o & 7, lane = (o >> 3) & 63, q = o >> 9;
            int nt = q & 15;  // kt = q>>4
            int k = (q >> 4) * 32 + (lane >> 4) * 8 + j;
            int n = nt * 16 + (lane & 15);
            v = Wdh[n * 128 + k];               // B[k][n] = Wdh[n][k]
        } else if (i < 65536) {                 // WhB
            int o = i - 32768, j = o & 7, lane = (o >> 3) & 63, q = o >> 9;
            int nt = q & 7;
            int k = (q >> 3) * 32 + (lane >> 4) * 8 + j;
            int n = nt * 16 + (lane & 15);
            v = Wh[n * 256 + k];
        } else if (i < 81920) {                 // WfB (diag masked)
            int o = i - 65536, j = o & 7, lane = (o >> 3) & 63, q = o >> 9;
            int nt = q & 7;
            int k = (q >> 3) * 32 + (lane >> 4) * 8 + j;
            int n = nt * 16 + (lane & 15);
            v = (k == n) ? 0.f : Wf[n * 128 + k];
        } else if (i < 114688) {                // WcB
            int o = i - 81920, j = o & 7, lane = (o >> 3) & 63, q = o >> 9;
            int nt = q & 7;
            int k = (q >> 3) * 32 + (lane >> 4) * 8 + j;
            int n = nt * 16 + (lane & 15);
            v = Wc[n * 256 + k];
        } else {                                // W2B
            int o = i - 114688, j = o & 7, lane = (o >> 3) & 63, q = o >> 9;
            int nt = q & 63;
            int k = (q >> 6) * 32 + (lane >> 4) * 8 + j;
            int g = nt * 16 + (lane & 15);
            v = (k < 256) ? Wih[g * 256 + k] : Whh[g * 256 + (k - 256)];
        }
        wsu[i] = f2bf(v);
    }
}

// ---------------- msum[t] ----------------
__global__ void msum_kernel(const float* __restrict__ mask, float* __restrict__ msum) {
    int t = blockIdx.x;
    float s = 0.f;
    for (int i = threadIdx.x; i < BB * FF; i += 256) {
        int b = i >> 7, f = i & 127;
        s += mask[((long)b * TT + t) * FF + f];
    }
    __shared__ float red[4];
    for (int off = 32; off; off >>= 1) s += __shfl_down(s, off);
    if ((threadIdx.x & 63) == 0) red[threadIdx.x >> 6] = s;
    __syncthreads();
    if (threadIdx.x == 0) msum[t] = red[0] + red[1] + red[2] + red[3];
}

// ---------------- main: 32 blocks x 512 threads (8 waves), 16 rows/block, MFMA ----------------
__launch_bounds__(512)
__global__ void rits_main(const float* __restrict__ values, const float* __restrict__ mask,
                          const float* __restrict__ deltas,
                          const float* __restrict__ bdh, const float* __restrict__ Wdx,
                          const float* __restrict__ bdx, const float* __restrict__ bh,
                          const float* __restrict__ bf_, const float* __restrict__ bc_,
                          const float* __restrict__ bih, const float* __restrict__ bhh,
                          const uint16_t* __restrict__ wsu,
                          float* __restrict__ part, float* __restrict__ out_imp) {
    __shared__ __align__(16) uint16_t dA[4 * 512];     // d,  A-layout, K=128
    __shared__ __align__(16) uint16_t gxmA[8 * 512];   // [gx|m], K=256
    __shared__ __align__(16) uint16_t hA[8 * 512];     // decayed h, K=256
    __shared__ __align__(16) uint16_t xcA[4 * 512];    // x_c, K=128
    __shared__ __align__(16) uint16_t actA[16 * 512];  // [cc|m|h], K=512
    __shared__ __align__(16) float x32[16 * 132];
    __shared__ __align__(16) float m32[16 * 132];
    __shared__ __align__(16) float h32[16 * 264];
    __shared__ __align__(16) float g32[16 * 1032];
    __shared__ float wred[3][8];

    const int tid = threadIdx.x;
    const int blk = blockIdx.x;
    const int r0 = blk * MR;
    const int w = tid >> 6;        // wave 0..7
    const int L = tid & 63;        // lane
    const int col = L & 15;
    const int q = L >> 4;

    const s8v* WDHB = (const s8v*)(wsu + E_WDH);
    const s8v* WHB  = (const s8v*)(wsu + E_WH);
    const s8v* WFB  = (const s8v*)(wsu + E_WF);
    const s8v* WCB  = (const s8v*)(wsu + E_WC);
    const s8v* W2B  = (const s8v*)(wsu + E_W2);

    // ---- hoisted per-thread constants ----
    const int rowi = tid >> 5;          // IN-stage row
    const int f4 = (tid & 31) * 4;      // IN-stage f base
    float cwdx[4], cbdx[4];
    #pragma unroll
    for (int e = 0; e < 4; ++e) {
        cwdx[e] = Wdx[(f4 + e) * FF + (f4 + e)];
        cbdx[e] = bdx[f4 + e];
    }
    const float bdh0 = bdh[32 * w + col];
    const float bdh1 = bdh[32 * w + 16 + col];
    const int fw = 16 * w + col;        // this wave's f column (N=128 stages)
    const float c_bh = bh[fw], c_bf = bf_[fw], c_bc = bc_[fw];
    float gb[8];
    #pragma unroll
    for (int e = 0; e < 8; ++e) {
        int g = (8 * w + e) * 16 + col;
        gb[e] = bih[g] + bhh[g];
    }
    const int row5 = tid >> 5;          // LSTM-stage row
    const int h8 = (tid & 31) * 8;

    float cst[8];
    #pragma unroll
    for (int e = 0; e < 8; ++e) cst[e] = 0.f;
    for (int i = tid; i < 16 * 264; i += 512) h32[i] = 0.f;
    __syncthreads();

    for (int t = 0; t < TT; ++t) {
        // ================= IN: load x,m,d; gx; fill A-arrays =================
        {
            long base = ((long)(r0 + rowi) * TT + t) * FF + f4;
            float4 xv = *(const float4*)(values + base);
            float4 mv = *(const float4*)(mask + base);
            float4 dv = *(const float4*)(deltas + base);
            *(float4*)(x32 + rowi * 132 + f4) = xv;
            *(float4*)(m32 + rowi * 132 + f4) = mv;
            float g0 = fexp(-fmaxf(dv.x * cwdx[0] + cbdx[0], 0.f));
            float g1 = fexp(-fmaxf(dv.y * cwdx[1] + cbdx[1], 0.f));
            float g2 = fexp(-fmaxf(dv.z * cwdx[2] + cbdx[2], 0.f));
            float g3 = fexp(-fmaxf(dv.w * cwdx[3] + cbdx[3], 0.f));
            *(uint2*)(dA + aidx(f4, rowi)) = pack4(dv.x, dv.y, dv.z, dv.w);
            *(uint2*)(gxmA + aidx(f4, rowi)) = pack4(g0, g1, g2, g3);
            uint2 pm = pack4(mv.x, mv.y, mv.z, mv.w);
            *(uint2*)(gxmA + aidx(128 + f4, rowi)) = pm;
            *(uint2*)(actA + aidx(128 + f4, rowi)) = pm;
        }
        __syncthreads();  // S1

        // ================= G1: gamma_h GEMM + decay h =================
        {
            s8v ad[4];
            #pragma unroll
            for (int kt = 0; kt < 4; ++kt) ad[kt] = *(const s8v*)(dA + kt * 512 + L * 8);
            f4v ac0 = {0.f, 0.f, 0.f, 0.f}, ac1 = ac0;
            #pragma unroll
            for (int kt = 0; kt < 4; ++kt) {
                s8v b0 = WDHB[(kt * 16 + 2 * w) * 64 + L];
                s8v b1 = WDHB[(kt * 16 + 2 * w + 1) * 64 + L];
                ac0 = __builtin_amdgcn_mfma_f32_16x16x32_bf16(ad[kt], b0, ac0, 0, 0, 0);
                ac1 = __builtin_amdgcn_mfma_f32_16x16x32_bf16(ad[kt], b1, ac1, 0, 0, 0);
            }
            #pragma unroll
            for (int r = 0; r < 4; ++r) {
                int m = q * 4 + r;
                int n0 = 32 * w + col;
                float hd0 = h32[m * 264 + n0] * fexp(-fmaxf(ac0[r] + bdh0, 0.f));
                uint16_t hb0 = f2bf(hd0);
                hA[aidx(n0, m)] = hb0;
                actA[aidx(256 + n0, m)] = hb0;
                int n1 = n0 + 16;
                float hd1 = h32[m * 264 + n1] * fexp(-fmaxf(ac1[r] + bdh1, 0.f));
                uint16_t hb1 = f2bf(hd1);
                hA[aidx(n1, m)] = hb1;
                actA[aidx(256 + n1, m)] = hb1;
            }
        }
        __syncthreads();  // S2

        // ================= G2: x_h GEMM, loss1, x_c =================
        float xh[4], xr[4], mr[4], acc1 = 0.f;
        {
            s8v ah[8];
            #pragma unroll
            for (int kt = 0; kt < 8; ++kt) ah[kt] = *(const s8v*)(hA + kt * 512 + L * 8);
            f4v a = {0.f, 0.f, 0.f, 0.f};
            #pragma unroll
            for (int kt = 0; kt < 8; ++kt) {
                s8v b = WHB[(kt * 8 + w) * 64 + L];
                a = __builtin_amdgcn_mfma_f32_16x16x32_bf16(ah[kt], b, a, 0, 0, 0);
            }
            #pragma unroll
            for (int r = 0; r < 4; ++r) {
                int m = q * 4 + r;
                xh[r] = a[r] + c_bh;
                xr[r] = x32[m * 132 + fw];
                mr[r] = m32[m * 132 + fw];
                acc1 += fabsf(xh[r] - xr[r]) * mr[r];
                float xc = mr[r] * xr[r] + (1.f - mr[r]) * xh[r];
                xcA[aidx(fw, m)] = f2bf(xc);
            }
        }
        __syncthreads();  // S3

        // ================= G3: z_h + alpha GEMMs, c_h, losses, c_c =================
        {
            s8v axc[4];
            #pragma unroll
            for (int kt = 0; kt < 4; ++kt) axc[kt] = *(const s8v*)(xcA + kt * 512 + L * 8);
            s8v agm[8];
            #pragma unroll
            for (int kt = 0; kt < 8; ++kt) agm[kt] = *(const s8v*)(gxmA + kt * 512 + L * 8);
            f4v az = {0.f, 0.f, 0.f, 0.f}, aa = az;
            #pragma unroll
            for (int kt = 0; kt < 4; ++kt) {
                s8v b = WFB[(kt * 8 + w) * 64 + L];
                az = __builtin_amdgcn_mfma_f32_16x16x32_bf16(axc[kt], b, az, 0, 0, 0);
            }
            #pragma unroll
            for (int kt = 0; kt < 8; ++kt) {
                s8v b = WCB[(kt * 8 + w) * 64 + L];
                aa = __builtin_amdgcn_mfma_f32_16x16x32_bf16(agm[kt], b, aa, 0, 0, 0);
            }
            float acc2 = 0.f, acc3 = 0.f;
            #pragma unroll
            for (int r = 0; r < 4; ++r) {
                int m = q * 4 + r;
                float zh = az[r] + c_bf;
                float al = aa[r] + c_bc;
                float ch = al * zh + (1.f - al) * xh[r];
                acc2 += fabsf(zh - xr[r]) * mr[r];
                acc3 += fabsf(ch - xr[r]) * mr[r];
                float cc = mr[r] * xr[r] + (1.f - mr[r]) * ch;
                out_imp[((long)(r0 + m) * TT + t) * FF + fw] = cc;
                actA[aidx(fw, m)] = f2bf(cc);
            }
            float a1 = acc1, a2 = acc2, a3 = acc3;
            for (int off = 32; off; off >>= 1) {
                a1 += __shfl_down(a1, off);
                a2 += __shfl_down(a2, off);
                a3 += __shfl_down(a3, off);
            }
            if (L == 0) { wred[0][w] = a1; wred[1][w] = a2; wred[2][w] = a3; }
        }
        __syncthreads();  // S4

        if (tid < 3) {
            float s = 0.f;
            #pragma unroll
            for (int e = 0; e < 8; ++e) s += wred[tid][e];
            part[((long)tid * TT + t) * NB + blk] = s;
        }
        // ================= G4: gates GEMM (K=512, N=1024) =================
        {
            s8v aact[16];
            #pragma unroll
            for (int kt = 0; kt < 16; ++kt) aact[kt] = *(const s8v*)(actA + kt * 512 + L * 8);
            for (int nt8 = 0; nt8 < 8; ++nt8) {
                f4v g = {0.f, 0.f, 0.f, 0.f};
                #pragma unroll
                for (int kt = 0; kt < 16; ++kt) {
                    s8v b = W2B[(kt * 64 + 8 * w + nt8) * 64 + L];
                    g = __builtin_amdgcn_mfma_f32_16x16x32_bf16(aact[kt], b, g, 0, 0, 0);
                }
                int gidx = (8 * w + nt8) * 16 + col;
                #pragma unroll
                for (int r = 0; r < 4; ++r)
                    g32[(q * 4 + r) * 1032 + gidx] = g[r] + gb[nt8];
            }
        }
        __syncthreads();  // S5

        // ================= G5: LSTM pointwise =================
        {
            const float* gr = g32 + row5 * 1032;
            float4 gi0 = *(const float4*)(gr + h8);
            float4 gi1 = *(const float4*)(gr + h8 + 4);
            float4 gf0 = *(const float4*)(gr + 256 + h8);
            float4 gf1 = *(const float4*)(gr + 256 + h8 + 4);
            float4 gg0 = *(const float4*)(gr + 512 + h8);
            float4 gg1 = *(const float4*)(gr + 512 + h8 + 4);
            float4 go0 = *(const float4*)(gr + 768 + h8);
            float4 go1 = *(const float4*)(gr + 768 + h8 + 4);
            float gi[8] = {gi0.x, gi0.y, gi0.z, gi0.w, gi1.x, gi1.y, gi1.z, gi1.w};
            float gf[8] = {gf0.x, gf0.y, gf0.z, gf0.w, gf1.x, gf1.y, gf1.z, gf1.w};
            float gg[8] = {gg0.x, gg0.y, gg0.z, gg0.w, gg1.x, gg1.y, gg1.z, gg1.w};
            float go[8] = {go0.x, go0.y, go0.z, go0.w, go1.x, go1.y, go1.z, go1.w};
            float hn[8];
            #pragma unroll
            for (int e = 0; e < 8; ++e) {
                cst[e] = fsigm(gf[e]) * cst[e] + fsigm(gi[e]) * ftanh(gg[e]);
                hn[e] = fsigm(go[e]) * ftanh(cst[e]);
            }
            float* hr = h32 + row5 * 264 + h8;
            *(float4*)(hr) = make_float4(hn[0], hn[1], hn[2], hn[3]);
            *(float4*)(hr + 4) = make_float4(hn[4], hn[5], hn[6], hn[7]);
        }
        __syncthreads();  // S6 (orders h32/g32 for next step)
    }
}

// ---------------- finisher ----------------
__global__ void finisher(const float* __restrict__ part, const float* __restrict__ msum,
                         float* __restrict__ out2) {
    int t = threadIdx.x;
    float s1 = 0.f, s2 = 0.f, s3 = 0.f;
    const float* p1 = part + ((long)0 * TT + t) * NB;
    const float* p2 = part + ((long)1 * TT + t) * NB;
    const float* p3 = part + ((long)2 * TT + t) * NB;
    for (int b = 0; b < NB; ++b) { s1 += p1[b]; s2 += p2[b]; s3 += p3[b]; }
    float den = msum[t] + EPSL;
    float l12 = (s1 + s2) / den;
    float l3 = s3 / den;
    float xl = l12 + (float)(TT - t) * l3;
    float ml = l3;
    __shared__ float r1[4], r2[4];
    for (int off = 32; off; off >>= 1) {
        xl += __shfl_down(xl, off);
        ml += __shfl_down(ml, off);
    }
    if ((t & 63) == 0) { r1[t >> 6] = xl; r2[t >> 6] = ml; }
    __syncthreads();
    if (t == 0) {
        float X = r1[0] + r1[1] + r1[2] + r1[3];
        float M = r2[0] + r2[1] + r2[2] + r2[3];
        out2[0] = X / (float)(TT * 3);
        out2[1] = M / (float)TT;
    }
}

extern "C" void kernel_launch(void* const* d_in, const int* in_sizes, int n_in,
                              void* d_out, int out_size, void* d_ws, size_t ws_size,
                              hipStream_t stream) {
    const float* values = (const float*)d_in[0];
    const float* mask   = (const float*)d_in[1];
    const float* deltas = (const float*)d_in[2];
    const float* Wdh = (const float*)d_in[3];
    const float* bdh = (const float*)d_in[4];
    const float* Wdx = (const float*)d_in[5];
    const float* bdx = (const float*)d_in[6];
    const float* Wh  = (const float*)d_in[7];
    const float* bh  = (const float*)d_in[8];
    const float* Wf  = (const float*)d_in[9];
    const float* bf_ = (const float*)d_in[10];
    const float* Wc  = (const float*)d_in[11];
    const float* bc_ = (const float*)d_in[12];
    const float* Wih = (const float*)d_in[13];
    const float* Whh = (const float*)d_in[14];
    const float* bih = (const float*)d_in[15];
    const float* bhh = (const float*)d_in[16];

    float* out = (float*)d_out;
    uint16_t* wsu = (uint16_t*)d_ws;
    float* msum = (float*)((char*)d_ws + OFF_MSUM);
    float* part = (float*)((char*)d_ws + OFF_PART);

    prep_weights<<<2496, 256, 0, stream>>>(Wdh, Wh, Wf, Wc, Wih, Whh, wsu);
    msum_kernel<<<TT, 256, 0, stream>>>(mask, msum);
    rits_main<<<NB, 512, 0, stream>>>(values, mask, deltas, bdh, Wdx, bdx,
                                      bh, bf_, bc_, bih, bhh, wsu, part, out);
    finisher<<<1, 256, 0, stream>>>(part, msum, out + (long)BB * TT * FF);
}